// Round 11
// baseline (249.906 us; speedup 1.0000x reference)
//
#include <hip/hip_runtime.h>
#include <math.h>

#define IMG 512
#define TW 64      // output tile width
#define TH 16      // output tile height
#define RS 82      // V row stride floats: 82%32=18 -> 16 row bases cover all 16 even
                   // bank residues (h-read = 2 lanes/bank, verified round 5/9)
#define RAWS 84    // raw row stride floats: 16B-aligned (84%4==0), rows rotate
                   // 20 mod 32 banks -> near-uniform v-read b128 spread
#define NQ 20      // col-quads per intermediate row (cols x0-8 .. x0+71)
#define NV2 (8 * NQ)   // 160 two-row vertical tasks (concentrated: round-10 lesson)
#define BT 256     // 4 waves
#define NCH (26 * 20)  // 520 staging chunks (float4) per image
#define MMB 1024   // minmax stage-1 blocks

struct W11 { float w[11]; };

__device__ __forceinline__ unsigned omap(float f) {
  unsigned b = __float_as_uint(f);
  return (b & 0x80000000u) ? ~b : (b | 0x80000000u);
}
__device__ __forceinline__ float ounmap(unsigned u) {
  return __uint_as_float((u & 0x80000000u) ? (u ^ 0x80000000u) : ~u);
}

// Min/max in ONE kernel: per-block reduce, then device-scope atomics into
// ws[0]=max, ws[1]=min (host pre-inits via hipMemsetAsync; saves a launch).
__global__ __launch_bounds__(256) void minmax_part(const float4* __restrict__ img,
                                                   int n4, unsigned* __restrict__ ws) {
  unsigned mx = 0u, mn = 0xFFFFFFFFu;
  int stride = gridDim.x * blockDim.x;
  for (int i = blockIdx.x * blockDim.x + threadIdx.x; i < n4; i += stride) {
    float4 v = img[i];
    unsigned a = omap(v.x), b = omap(v.y), c = omap(v.z), d = omap(v.w);
    mx = max(mx, max(max(a, b), max(c, d)));
    mn = min(mn, min(min(a, b), min(c, d)));
  }
  #pragma unroll
  for (int off = 32; off > 0; off >>= 1) {
    mx = max(mx, __shfl_down(mx, off));
    mn = min(mn, __shfl_down(mn, off));
  }
  __shared__ unsigned smx[4], smn[4];
  int lane = threadIdx.x & 63, wv = threadIdx.x >> 6;
  if (lane == 0) { smx[wv] = mx; smn[wv] = mn; }
  __syncthreads();
  if (threadIdx.x == 0) {
    mx = max(max(smx[0], smx[1]), max(smx[2], smx[3]));
    mn = min(min(smn[0], smn[1]), min(smn[2], smn[3]));
    atomicMax(&ws[0], mx);
    atomicMin(&ws[1], mn);
  }
}

// One TWO-ROW vertical task fed from LDS-staged raw data: 11-tap v-conv of
// {a, b, a^2+b^2, a*b} for rows (2p, 2p+1) x 4 cols from 12 LDS rows.
// Round-11: sources from Raw[] (zero-padded at staging) -> no bounds logic,
// ~120cyc LDS latency instead of 200-900cyc global (the round-9 stall source;
// compiler pins global MLP to ~3 to hold 64 VGPR -- round-6 finding).
__device__ __forceinline__ void vtask2(int t, const W11& wv,
                                       const float (*Raw)[26][RAWS],
                                       float (*V)[TH][RS]) {
  const int p = t / NQ;              // row-pair 0..7
  const int q = t - p * NQ;          // 0..19

  float A[4][4], B[4][4];            // constant-indexed after unroll (SROA-safe)
  #pragma unroll
  for (int f = 0; f < 4; ++f)
    #pragma unroll
    for (int c = 0; c < 4; ++c) { A[f][c] = 0.f; B[f][c] = 0.f; }

  const float* r1 = &Raw[0][2 * p][4 * q];   // rows 2p .. 2p+11, 16B-aligned
  const float* r2 = &Raw[1][2 * p][4 * q];

#define VSTEP2(k)                                                             \
  {                                                                           \
    float4 a = *(const float4*)(r1 + (k) * RAWS);                             \
    float4 b = *(const float4*)(r2 + (k) * RAWS);                             \
    float sx = a.x * a.x + b.x * b.x, sy = a.y * a.y + b.y * b.y;             \
    float sz = a.z * a.z + b.z * b.z, sw = a.w * a.w + b.w * b.w;             \
    float px = a.x * b.x, py = a.y * b.y, pz = a.z * b.z, pw = a.w * b.w;     \
    if ((k) < 11) { float w = wv.w[(k)];                                      \
      A[0][0] += w * a.x; A[0][1] += w * a.y; A[0][2] += w * a.z; A[0][3] += w * a.w; \
      A[1][0] += w * b.x; A[1][1] += w * b.y; A[1][2] += w * b.z; A[1][3] += w * b.w; \
      A[2][0] += w * sx;  A[2][1] += w * sy;  A[2][2] += w * sz;  A[2][3] += w * sw;  \
      A[3][0] += w * px;  A[3][1] += w * py;  A[3][2] += w * pz;  A[3][3] += w * pw; }\
    if ((k) > 0) { float w = wv.w[(k) - 1];                                   \
      B[0][0] += w * a.x; B[0][1] += w * a.y; B[0][2] += w * a.z; B[0][3] += w * a.w; \
      B[1][0] += w * b.x; B[1][1] += w * b.y; B[1][2] += w * b.z; B[1][3] += w * b.w; \
      B[2][0] += w * sx;  B[2][1] += w * sy;  B[2][2] += w * sz;  B[2][3] += w * sw;  \
      B[3][0] += w * px;  B[3][1] += w * py;  B[3][2] += w * pz;  B[3][3] += w * pw; }\
  }

  VSTEP2(0)  VSTEP2(1)  VSTEP2(2)  VSTEP2(3)  VSTEP2(4)  VSTEP2(5)
  VSTEP2(6)  VSTEP2(7)  VSTEP2(8)  VSTEP2(9)  VSTEP2(10) VSTEP2(11)
#undef VSTEP2

  // b64 writes, consecutive lanes -> consecutive addresses (clean class).
  const int r0 = 2 * p;
  *(float2*)&V[0][r0][4 * q]         = make_float2(A[0][0], A[0][1]);
  *(float2*)&V[0][r0][4 * q + 2]     = make_float2(A[0][2], A[0][3]);
  *(float2*)&V[1][r0][4 * q]         = make_float2(A[1][0], A[1][1]);
  *(float2*)&V[1][r0][4 * q + 2]     = make_float2(A[1][2], A[1][3]);
  *(float2*)&V[2][r0][4 * q]         = make_float2(A[2][0], A[2][1]);
  *(float2*)&V[2][r0][4 * q + 2]     = make_float2(A[2][2], A[2][3]);
  *(float2*)&V[3][r0][4 * q]         = make_float2(A[3][0], A[3][1]);
  *(float2*)&V[3][r0][4 * q + 2]     = make_float2(A[3][2], A[3][3]);
  *(float2*)&V[0][r0 + 1][4 * q]     = make_float2(B[0][0], B[0][1]);
  *(float2*)&V[0][r0 + 1][4 * q + 2] = make_float2(B[0][2], B[0][3]);
  *(float2*)&V[1][r0 + 1][4 * q]     = make_float2(B[1][0], B[1][1]);
  *(float2*)&V[1][r0 + 1][4 * q + 2] = make_float2(B[1][2], B[1][3]);
  *(float2*)&V[2][r0 + 1][4 * q]     = make_float2(B[2][0], B[2][1]);
  *(float2*)&V[2][r0 + 1][4 * q + 2] = make_float2(B[2][2], B[2][3]);
  *(float2*)&V[3][r0 + 1][4 * q]     = make_float2(B[3][0], B[3][1]);
  *(float2*)&V[3][r0 + 1][4 * q + 2] = make_float2(B[3][2], B[3][3]);
}

// Fused SSIM, round-11: STAGE raw tile -> LDS (bulk pipelined loads, each
// global byte touched once per block), v-conv from LDS, h-conv from V.
// Shell otherwise = round 9 (measured best): concentrated v-tasks, RS=82
// bank layout, b64-only V traffic. LDS 38.5KB -> 4 blocks/CU (16 waves);
// trade accepted because phase stalls shrink (LDS-fed v, pipelined staging).
__global__ __launch_bounds__(BT, 4) void ssim_k(const float* __restrict__ img1,
                                                const float* __restrict__ img2,
                                                float* __restrict__ out,
                                                const unsigned* __restrict__ ws,
                                                W11 wv) {
  __shared__ float Raw[2][26][RAWS];   // 17472 B: zero-padded raw tile, both images
  __shared__ float V[4][TH][RS];       // 20992 B: v-conv fields

  const int tid = threadIdx.x;
  const int bx = blockIdx.x, by = blockIdx.y, n = blockIdx.z;
  const float* p1 = img1 + (size_t)n * IMG * IMG;
  const float* p2 = img2 + (size_t)n * IMG * IMG;
  const int x0 = bx * TW;
  const int y0 = by * TH;

  // C1/C2 (scalar loads issued early; needed in the epilogue)
  float L = ounmap(ws[0]) - ounmap(ws[1]);
  if (L == 0.f) L = 5.f;
  float C1 = 0.01f * L; C1 *= C1;
  float C2 = 0.03f * L; C2 *= C2;

  // ---- phase 0: stage 26 rows x 80 cols of both images into LDS ----
  // 520 float4 chunks; chunk c -> (row = c/20, quad = c%20). All 256 threads,
  // 2 rounds + tail: independent loads issue back-to-back (latency pipelined).
  {
    const int gx0 = x0 - 8;
    const int gy0 = y0 - 5;
#define STAGE(c)                                                              \
    {                                                                         \
      int row = (c) / 20;                                                     \
      int qd  = (c) - row * 20;                                               \
      int gy = gy0 + row, gx = gx0 + 4 * qd;                                  \
      float4 a = make_float4(0.f, 0.f, 0.f, 0.f);                             \
      float4 b = make_float4(0.f, 0.f, 0.f, 0.f);                             \
      if (((unsigned)gy < IMG) & ((unsigned)gx < IMG)) {                      \
        a = *(const float4*)(p1 + (size_t)gy * IMG + gx);                     \
        b = *(const float4*)(p2 + (size_t)gy * IMG + gx);                     \
      }                                                                       \
      *(float4*)&Raw[0][row][4 * qd] = a;                                     \
      *(float4*)&Raw[1][row][4 * qd] = b;                                     \
    }
    STAGE(tid)
    STAGE(tid + 256)
    if (tid < NCH - 512) STAGE(tid + 512)   // chunks 512..519
#undef STAGE
  }
  __syncthreads();

  // ---- phase 1: 160 two-row v-tasks on threads 0..159 (concentrated:
  // round-10 showed spreading at partial lane density costs 1.6x issue) ----
  if (tid < NV2) vtask2(tid, wv, Raw, V);
  __syncthreads();

  // ---- phase 2: h-conv, byte-identical to round 9 (verified 2 lanes/bank) ----
  {
    const int r  = tid & 15;           // row 0..15
    const int c4 = (tid >> 4) << 2;    // output col offset 0..60

    float acc[4][4];
    #pragma unroll
    for (int f = 0; f < 4; ++f)
      #pragma unroll
      for (int c = 0; c < 4; ++c) acc[f][c] = 0.f;

    float v[16];   // function scope, constant indices only (SROA-safe)
    #pragma unroll
    for (int f = 0; f < 4; ++f) {
      const float* row = &V[f][r][c4 + 2];
      float2 g0 = *(const float2*)(row + 0);
      float2 g1 = *(const float2*)(row + 2);
      float2 g2 = *(const float2*)(row + 4);
      float2 g3 = *(const float2*)(row + 6);
      float2 g4 = *(const float2*)(row + 8);
      float2 g5 = *(const float2*)(row + 10);
      float2 g6 = *(const float2*)(row + 12);
      float2 g7 = *(const float2*)(row + 14);
      v[0]  = g0.x; v[1]  = g0.y; v[2]  = g1.x; v[3]  = g1.y;
      v[4]  = g2.x; v[5]  = g2.y; v[6]  = g3.x; v[7]  = g3.y;
      v[8]  = g4.x; v[9]  = g4.y; v[10] = g5.x; v[11] = g5.y;
      v[12] = g6.x; v[13] = g6.y; v[14] = g7.x; v[15] = g7.y;
      #pragma unroll
      for (int k = 0; k < 11; ++k) {
        float wk = wv.w[k];
        #pragma unroll
        for (int c = 0; c < 4; ++c) acc[f][c] += wk * v[c + 1 + k];
      }
    }

    float res[4];
    #pragma unroll
    for (int c = 0; c < 4; ++c) {
      float mu1 = acc[0][c], mu2 = acc[1][c];
      float mu1s = mu1 * mu1, mu2s = mu2 * mu2, mu12 = mu1 * mu2;
      float sS  = acc[2][c] - mu1s - mu2s;   // sigma1_sq + sigma2_sq
      float s12 = acc[3][c] - mu12;
      float num = (2.f * mu12 + C1) * (2.f * s12 + C2);
      float den = (mu1s + mu2s + C1) * (sS + C2);
      res[c] = num / den;
    }
    float* op = out + (size_t)n * IMG * IMG + (size_t)(y0 + r) * IMG + x0 + c4;
    *(float4*)op = make_float4(res[0], res[1], res[2], res[3]);
  }
}

extern "C" void kernel_launch(void* const* d_in, const int* in_sizes, int n_in,
                              void* d_out, int out_size, void* d_ws, size_t ws_size,
                              hipStream_t stream) {
  const float* img1 = (const float*)d_in[0];
  const float* img2 = (const float*)d_in[1];
  float* out = (float*)d_out;
  unsigned* ws = (unsigned*)d_ws;      // [0]=max (omap), [1]=min (omap)
  int n = in_sizes[0];             // 32*1*512*512
  int batch = n / (IMG * IMG);     // 32

  // Gaussian window, center at ws/2 = 5.5 (asymmetric!), normalized
  W11 wv;
  double g[11], s = 0.0;
  for (int i = 0; i < 11; ++i) { double d = i - 5.5; g[i] = exp(-(d * d) / 4.5); s += g[i]; }
  for (int i = 0; i < 11; ++i) wv.w[i] = (float)(g[i] / s);

  // init ws for atomics: ws[0]=0 (max identity), ws[1]=0xFFFFFFFF (min identity)
  hipMemsetAsync(ws, 0, 4, stream);
  hipMemsetAsync(ws + 1, 0xFF, 4, stream);

  minmax_part<<<MMB, 256, 0, stream>>>((const float4*)img1, n / 4, ws);
  dim3 grid(IMG / TW, IMG / TH, batch);
  ssim_k<<<grid, BT, 0, stream>>>(img1, img2, out, ws, wv);
}